// Round 1
// baseline (727.198 us; speedup 1.0000x reference)
//
#include <hip/hip_runtime.h>
#include <hip/hip_bf16.h>
#include <math.h>

#define E_ 8
#define D_ 1024
#define F_ 4096
#define N_ 2048

using f32x4  = __attribute__((ext_vector_type(4))) float;
using bhalf8 = __attribute__((ext_vector_type(8))) short;
using bhalf4 = __attribute__((ext_vector_type(4))) short;

__device__ __forceinline__ short f2bf(float f) {
    union { float f; unsigned u; } v; v.f = f;
    unsigned r = v.u + 0x7FFFu + ((v.u >> 16) & 1u);   // RNE
    return (short)(r >> 16);
}

__device__ __forceinline__ float gelu_exact(float x) {
    return 0.5f * x * (1.0f + erff(x * 0.70710678118654752f));
}

// ---------------- routing ----------------

__global__ void k_zero(int* counts) {
    if (threadIdx.x < E_) counts[threadIdx.x] = 0;
}

__global__ void k_route(const float* __restrict__ x, const float* __restrict__ gw,
                        int* __restrict__ counts, int* __restrict__ top_idx,
                        float* __restrict__ top_w, int* __restrict__ slot_in) {
    const int wid  = threadIdx.x >> 6;
    const int lane = threadIdx.x & 63;
    const int n = blockIdx.x * 4 + wid;
    if (n >= N_) return;
    float part[E_];
#pragma unroll
    for (int e = 0; e < E_; e++) part[e] = 0.f;
    const float* xr = x + (size_t)n * D_;
#pragma unroll
    for (int j = 0; j < 4; j++) {
        const int d = lane * 4 + j * 256;
        const float4 xv = *(const float4*)(xr + d);
#pragma unroll
        for (int e = 0; e < E_; e++) {
            const float4 gv = *(const float4*)(gw + (size_t)e * D_ + d);
            part[e] += xv.x * gv.x + xv.y * gv.y + xv.z * gv.z + xv.w * gv.w;
        }
    }
#pragma unroll
    for (int e = 0; e < E_; e++)
        for (int o = 32; o; o >>= 1) part[e] += __shfl_xor(part[e], o);
    if (lane == 0) {
        int i0 = 0; float v0 = part[0];
        for (int e = 1; e < E_; e++) if (part[e] > v0) { v0 = part[e]; i0 = e; }
        int i1 = -1; float v1 = -3.4e38f;
        for (int e = 0; e < E_; e++) if (e != i0 && part[e] > v1) { v1 = part[e]; i1 = e; }
        const float e1 = expf(v1 - v0);
        const float w0 = 1.f / (1.f + e1);
        const float w1 = e1 / (1.f + e1);
        top_idx[n * 2] = i0;  top_idx[n * 2 + 1] = i1;
        top_w[n * 2]  = w0;   top_w[n * 2 + 1]  = w1;
        slot_in[n * 2]     = atomicAdd(&counts[i0], 1);
        slot_in[n * 2 + 1] = atomicAdd(&counts[i1], 1);
    }
}

__global__ void k_scan(const int* __restrict__ counts, int* __restrict__ offsets) {
    if (threadIdx.x == 0) {
        int s = 0;
        for (int e = 0; e < E_; e++) { offsets[e] = s; s += counts[e]; }
        offsets[E_] = s;
    }
}

__global__ void k_scatter(const int* __restrict__ top_idx, const int* __restrict__ slot_in,
                          const int* __restrict__ offsets, int* __restrict__ perm) {
    const int id = blockIdx.x * 256 + threadIdx.x;
    if (id >= 2 * N_) return;
    const int n = id >> 1, k = id & 1;
    const int e = top_idx[n * 2 + k];
    perm[offsets[e] + slot_in[n * 2 + k]] = n;
}

// ---------------- MFMA GEMM (C = A * B^T per expert bucket) ----------------
// A: gathered fp32 x rows (GEMM1) or packed bf16 h rows (GEMM2), [rows, KDIM]
// B: fp32 weights [E][NDIM][KDIM] row-major (so B^T layout: contiguous K)
// Out: packed [rows, NDIM], bf16 (+gelu) for GEMM1, fp32 for GEMM2.

template <int KDIM, int NDIM, bool A_IS_BF16, bool GELU_OUT, bool OUT_BF16>
__global__ __launch_bounds__(256, 2) void k_gemm(
    const void* __restrict__ Aglob, const float* __restrict__ Bglob,
    const int* __restrict__ counts, const int* __restrict__ offsets,
    const int* __restrict__ perm, void* __restrict__ Out)
{
    const int nt = blockIdx.x;
    const int e  = blockIdx.y >> 4;
    const int mt = blockIdx.y & 15;
    const int cnt = counts[e];
    const int mbase = mt * 128;
    if (mbase >= cnt) return;                    // dead tile, uniform exit
    const int roff  = offsets[e];
    const int nbase = nt * 128;

    __shared__ __attribute__((aligned(16))) short Alds[128][32];
    __shared__ __attribute__((aligned(16))) short Blds[128][32];
    __shared__ int sm_perm[128];

    const int t = threadIdx.x;
    if (!A_IS_BF16 && t < 128) {
        const int gm = mbase + t;
        sm_perm[t] = (gm < cnt) ? perm[roff + gm] : 0;
    }
    __syncthreads();

    const int lane = t & 63, wid = t >> 6;
    const int wr = wid >> 1, wc = wid & 1;       // 2x2 waves, 64x64 each
    const int fr = lane & 15, fq = lane >> 4;

    f32x4 acc[4][4];
#pragma unroll
    for (int i = 0; i < 4; i++)
#pragma unroll
        for (int j = 0; j < 4; j++) acc[i][j] = (f32x4){0.f, 0.f, 0.f, 0.f};

    const int kq = t & 7;                        // which 4-elem chunk of the 32-wide K row
    const int r0 = t >> 3;                       // 0..31
    const float* Bbase = Bglob + (size_t)e * NDIM * KDIM;

    for (int kb = 0; kb < KDIM; kb += 32) {
        // stage A tile [128 x 32] -> bf16 LDS
#pragma unroll
        for (int i = 0; i < 4; i++) {
            const int r = r0 + 32 * i;
            bhalf4 av = (bhalf4){0, 0, 0, 0};
            const int gm = mbase + r;
            if (gm < cnt) {
                if (A_IS_BF16) {
                    av = *(const bhalf4*)((const short*)Aglob + (size_t)(roff + gm) * KDIM + kb + kq * 4);
                } else {
                    const int tok = sm_perm[r];
                    const float4 v = *(const float4*)((const float*)Aglob + (size_t)tok * KDIM + kb + kq * 4);
                    av.x = f2bf(v.x); av.y = f2bf(v.y); av.z = f2bf(v.z); av.w = f2bf(v.w);
                }
            }
            *(bhalf4*)&Alds[r][kq * 4] = av;
        }
        // stage B tile [128 x 32] -> bf16 LDS
#pragma unroll
        for (int i = 0; i < 4; i++) {
            const int r = r0 + 32 * i;
            const float4 v = *(const float4*)(Bbase + (size_t)(nbase + r) * KDIM + kb + kq * 4);
            bhalf4 bv;
            bv.x = f2bf(v.x); bv.y = f2bf(v.y); bv.z = f2bf(v.z); bv.w = f2bf(v.w);
            *(bhalf4*)&Blds[r][kq * 4] = bv;
        }
        __syncthreads();

        bhalf8 af[4], bff[4];
#pragma unroll
        for (int i = 0; i < 4; i++) {
            af[i]  = *(const bhalf8*)&Alds[wr * 64 + i * 16 + fr][fq * 8];
            bff[i] = *(const bhalf8*)&Blds[wc * 64 + i * 16 + fr][fq * 8];
        }
#pragma unroll
        for (int mi = 0; mi < 4; mi++)
#pragma unroll
            for (int ni = 0; ni < 4; ni++)
                acc[mi][ni] = __builtin_amdgcn_mfma_f32_16x16x32_bf16(af[mi], bff[ni], acc[mi][ni], 0, 0, 0);
        __syncthreads();
    }

    // epilogue: C/D mapping col = lane&15, row = (lane>>4)*4 + reg  [m89-verified]
#pragma unroll
    for (int mi = 0; mi < 4; mi++) {
#pragma unroll
        for (int j = 0; j < 4; j++) {
            const int m  = wr * 64 + mi * 16 + fq * 4 + j;
            const int gm = mbase + m;
            if (gm >= cnt) continue;
#pragma unroll
            for (int ni = 0; ni < 4; ni++) {
                const int n = nbase + wc * 64 + ni * 16 + fr;
                float v = acc[mi][ni][j];
                if (GELU_OUT) v = gelu_exact(v);
                if (OUT_BF16)
                    ((short*)Out)[(size_t)(roff + gm) * NDIM + n] = f2bf(v);
                else
                    ((float*)Out)[(size_t)(roff + gm) * NDIM + n] = v;
            }
        }
    }
}

// ---------------- combine ----------------

__global__ void k_combine(const float* __restrict__ y,
                          const int* __restrict__ top_idx, const float* __restrict__ top_w,
                          const int* __restrict__ slot_in, const int* __restrict__ offsets,
                          float* __restrict__ out) {
    const int n = blockIdx.x;
    const int e0 = top_idx[n * 2], e1 = top_idx[n * 2 + 1];
    const int s0 = offsets[e0] + slot_in[n * 2];
    const int s1 = offsets[e1] + slot_in[n * 2 + 1];
    const float w0 = top_w[n * 2], w1 = top_w[n * 2 + 1];
    const int d = threadIdx.x * 4;
    const float4 a = *(const float4*)(y + (size_t)s0 * D_ + d);
    const float4 b = *(const float4*)(y + (size_t)s1 * D_ + d);
    float4 o;
    o.x = w0 * a.x + w1 * b.x;
    o.y = w0 * a.y + w1 * b.y;
    o.z = w0 * a.z + w1 * b.z;
    o.w = w0 * a.w + w1 * b.w;
    *(float4*)(out + (size_t)n * D_ + d) = o;
}

// ---------------- launch ----------------

extern "C" void kernel_launch(void* const* d_in, const int* in_sizes, int n_in,
                              void* d_out, int out_size, void* d_ws, size_t ws_size,
                              hipStream_t stream) {
    const float* x  = (const float*)d_in[0];
    const float* gw = (const float*)d_in[1];
    const float* w1 = (const float*)d_in[2];
    const float* w2 = (const float*)d_in[3];
    float* out = (float*)d_out;

    char* ws = (char*)d_ws;
    size_t o = 0;
    auto alloc = [&](size_t b) { size_t r = o; o += (b + 255) & ~(size_t)255; return r; };
    int*   counts  = (int*)(ws + alloc(E_ * 4));
    int*   offsets = (int*)(ws + alloc((E_ + 1) * 4));
    int*   top_idx = (int*)(ws + alloc(2 * N_ * 4));
    float* top_w   = (float*)(ws + alloc(2 * N_ * 4));
    int*   slot_in = (int*)(ws + alloc(2 * N_ * 4));
    int*   perm    = (int*)(ws + alloc(2 * N_ * 4));
    short* h       = (short*)(ws + alloc((size_t)2 * N_ * F_ * 2));
    float* yb      = (float*)(ws + alloc((size_t)2 * N_ * D_ * 4));

    hipLaunchKernelGGL(k_zero, dim3(1), dim3(64), 0, stream, counts);
    hipLaunchKernelGGL(k_route, dim3(N_ / 4), dim3(256), 0, stream, x, gw, counts, top_idx, top_w, slot_in);
    hipLaunchKernelGGL(k_scan, dim3(1), dim3(64), 0, stream, counts, offsets);
    hipLaunchKernelGGL(k_scatter, dim3((2 * N_ + 255) / 256), dim3(256), 0, stream,
                       top_idx, slot_in, offsets, perm);
    // GEMM1: h = gelu(X_gather @ w1^T)   [rows x F], K = D
    hipLaunchKernelGGL((k_gemm<D_, F_, false, true, true>), dim3(F_ / 128, E_ * 16), dim3(256), 0, stream,
                       (const void*)x, w1, counts, offsets, perm, (void*)h);
    // GEMM2: y = h @ w2^T                [rows x D], K = F
    hipLaunchKernelGGL((k_gemm<F_, D_, true, false, false>), dim3(D_ / 128, E_ * 16), dim3(256), 0, stream,
                       (const void*)h, w2, counts, offsets, perm, (void*)yb);
    hipLaunchKernelGGL(k_combine, dim3(N_), dim3(256), 0, stream,
                       yb, top_idx, top_w, slot_in, offsets, out);
}

// Round 2
// 588.491 us; speedup vs baseline: 1.2357x; 1.2357x over previous
//
#include <hip/hip_runtime.h>
#include <hip/hip_bf16.h>
#include <math.h>

#define E_ 8
#define D_ 1024
#define F_ 4096
#define N_ 2048

using f32x4  = __attribute__((ext_vector_type(4))) float;
using bhalf8 = __attribute__((ext_vector_type(8))) short;
using bhalf4 = __attribute__((ext_vector_type(4))) short;

__device__ __forceinline__ short f2bf(float f) {
    union { float f; unsigned u; } v; v.f = f;
    unsigned r = v.u + 0x7FFFu + ((v.u >> 16) & 1u);   // RNE
    return (short)(r >> 16);
}

__device__ __forceinline__ float gelu_exact(float x) {
    return 0.5f * x * (1.0f + erff(x * 0.70710678118654752f));
}

// async global -> LDS, 16B per lane; LDS dest is wave-uniform base + lane*16
__device__ __forceinline__ void async_copy16(void* lds, const void* g) {
    __builtin_amdgcn_global_load_lds(
        (const __attribute__((address_space(1))) unsigned int*)g,
        (__attribute__((address_space(3))) unsigned int*)lds,
        16, 0, 0);
}

// ---------------- fp32 -> bf16 bulk convert ----------------

__global__ void k_f32_to_bf16(const float* __restrict__ src, short* __restrict__ dst, int n4) {
    int i = blockIdx.x * 256 + threadIdx.x;
    const int stride = gridDim.x * 256;
    for (; i < n4; i += stride) {
        const float4 v = ((const float4*)src)[i];
        bhalf4 b;
        b.x = f2bf(v.x); b.y = f2bf(v.y); b.z = f2bf(v.z); b.w = f2bf(v.w);
        ((bhalf4*)dst)[i] = b;
    }
}

// ---------------- routing ----------------

__global__ void k_zero(int* counts) {
    if (threadIdx.x < E_) counts[threadIdx.x] = 0;
}

__global__ void k_route(const float* __restrict__ x, const float* __restrict__ gw,
                        int* __restrict__ counts, int* __restrict__ top_idx,
                        float* __restrict__ top_w, int* __restrict__ slot_in) {
    const int wid  = threadIdx.x >> 6;
    const int lane = threadIdx.x & 63;
    const int n = blockIdx.x * 4 + wid;
    if (n >= N_) return;
    float part[E_];
#pragma unroll
    for (int e = 0; e < E_; e++) part[e] = 0.f;
    const float* xr = x + (size_t)n * D_;
#pragma unroll
    for (int j = 0; j < 4; j++) {
        const int d = lane * 4 + j * 256;
        const float4 xv = *(const float4*)(xr + d);
#pragma unroll
        for (int e = 0; e < E_; e++) {
            const float4 gv = *(const float4*)(gw + (size_t)e * D_ + d);
            part[e] += xv.x * gv.x + xv.y * gv.y + xv.z * gv.z + xv.w * gv.w;
        }
    }
#pragma unroll
    for (int e = 0; e < E_; e++)
        for (int o = 32; o; o >>= 1) part[e] += __shfl_xor(part[e], o);
    if (lane == 0) {
        int i0 = 0; float v0 = part[0];
        for (int e = 1; e < E_; e++) if (part[e] > v0) { v0 = part[e]; i0 = e; }
        int i1 = -1; float v1 = -3.4e38f;
        for (int e = 0; e < E_; e++) if (e != i0 && part[e] > v1) { v1 = part[e]; i1 = e; }
        const float e1 = expf(v1 - v0);
        const float w0 = 1.f / (1.f + e1);
        const float w1 = e1 / (1.f + e1);
        top_idx[n * 2] = i0;  top_idx[n * 2 + 1] = i1;
        top_w[n * 2]  = w0;   top_w[n * 2 + 1]  = w1;
        slot_in[n * 2]     = atomicAdd(&counts[i0], 1);
        slot_in[n * 2 + 1] = atomicAdd(&counts[i1], 1);
    }
}

__global__ void k_scan(const int* __restrict__ counts, int* __restrict__ offsets) {
    if (threadIdx.x == 0) {
        int s = 0;
        for (int e = 0; e < E_; e++) { offsets[e] = s; s += counts[e]; }
        offsets[E_] = s;
    }
}

__global__ void k_scatter(const int* __restrict__ top_idx, const int* __restrict__ slot_in,
                          const int* __restrict__ offsets, int* __restrict__ perm) {
    const int id = blockIdx.x * 256 + threadIdx.x;
    if (id >= 2 * N_) return;
    const int n = id >> 1, k = id & 1;
    const int e = top_idx[n * 2 + k];
    perm[offsets[e] + slot_in[n * 2 + k]] = n;
}

// ---------------- MFMA GEMM (C = A * B^T per expert bucket), all-bf16 ----------------
// A: bf16. GATHER_A ? token matrix xb [N_][KDIM], rows gathered via perm
//                   : packed rows [totalRows][KDIM] starting at offsets[e].
// B: bf16 weights [E][NDIM][KDIM] row-major (contiguous K).
// Staging: global_load_lds 16B/lane (m97 structure, 2-barrier K-loop).

template <int KDIM, int NDIM, bool GATHER_A, bool GELU_OUT, bool OUT_BF16>
__global__ __launch_bounds__(256, 2) void k_gemm(
    const short* __restrict__ A, const short* __restrict__ B,
    const int* __restrict__ counts, const int* __restrict__ offsets,
    const int* __restrict__ perm, void* __restrict__ Out)
{
    const int nt = blockIdx.x;
    const int e  = blockIdx.y >> 4;
    const int mt = blockIdx.y & 15;
    const int cnt = counts[e];
    const int mbase = mt * 128;
    if (mbase >= cnt) return;                    // dead tile, uniform exit
    const int roff  = offsets[e];
    const int nbase = nt * 128;

    __shared__ __attribute__((aligned(16))) short Alds[128][32];
    __shared__ __attribute__((aligned(16))) short Blds[128][32];

    const int t = threadIdx.x;
    const int lane = t & 63, wid = t >> 6;
    const short* Bexp = B + (size_t)e * NDIM * KDIM;

    // staging geometry: tile = 128 rows x 32 bf16 = 512 x 16B chunks.
    // chunk c = wid*128 + i*64 + lane ; row = c>>2 ; col = (c&3)*8 bf16.
    const short* aS[2]; const short* bS[2];
    short* aD[2]; short* bD[2];
#pragma unroll
    for (int i = 0; i < 2; i++) {
        const int c   = wid * 128 + i * 64 + lane;
        const int r   = c >> 2;
        const int col = (c & 3) * 8;
        const int gm  = mbase + r;
        const int gmc = (gm < cnt) ? gm : 0;     // clamp dead rows to a valid row
        int arow;
        if (GATHER_A) arow = perm[roff + gmc];
        else          arow = roff + gmc;
        aS[i] = A + (size_t)arow * KDIM + col;
        bS[i] = Bexp + (size_t)(nbase + r) * KDIM + col;
        aD[i] = &Alds[0][0] + (size_t)(wid * 128 + i * 64) * 8;  // wave-uniform
        bD[i] = &Blds[0][0] + (size_t)(wid * 128 + i * 64) * 8;
    }

    const int wr = wid >> 1, wc = wid & 1;       // 2x2 waves, 64x64 each
    const int fr = lane & 15, fq = lane >> 4;

    f32x4 acc[4][4];
#pragma unroll
    for (int i = 0; i < 4; i++)
#pragma unroll
        for (int j = 0; j < 4; j++) acc[i][j] = (f32x4){0.f, 0.f, 0.f, 0.f};

    for (int kb = 0; kb < KDIM; kb += 32) {
#pragma unroll
        for (int i = 0; i < 2; i++) {
            async_copy16(aD[i], aS[i] + kb);
            async_copy16(bD[i], bS[i] + kb);
        }
        __syncthreads();                          // drains vmcnt, LDS ready

        bhalf8 af[4], bf[4];
#pragma unroll
        for (int i = 0; i < 4; i++) {
            af[i] = *(const bhalf8*)&Alds[wr * 64 + i * 16 + fr][fq * 8];
            bf[i] = *(const bhalf8*)&Blds[wc * 64 + i * 16 + fr][fq * 8];
        }
#pragma unroll
        for (int mi = 0; mi < 4; mi++)
#pragma unroll
            for (int ni = 0; ni < 4; ni++)
                acc[mi][ni] = __builtin_amdgcn_mfma_f32_16x16x32_bf16(af[mi], bf[ni], acc[mi][ni], 0, 0, 0);
        __syncthreads();                          // all reads done before overwrite
    }

    // epilogue: C/D mapping col = lane&15, row = (lane>>4)*4 + reg  [m89-verified]
#pragma unroll
    for (int mi = 0; mi < 4; mi++) {
#pragma unroll
        for (int j = 0; j < 4; j++) {
            const int m  = wr * 64 + mi * 16 + fq * 4 + j;
            const int gm = mbase + m;
            if (gm >= cnt) continue;
#pragma unroll
            for (int ni = 0; ni < 4; ni++) {
                const int n = nbase + wc * 64 + ni * 16 + fr;
                float v = acc[mi][ni][j];
                if (GELU_OUT) v = gelu_exact(v);
                if (OUT_BF16)
                    ((short*)Out)[(size_t)(roff + gm) * NDIM + n] = f2bf(v);
                else
                    ((float*)Out)[(size_t)(roff + gm) * NDIM + n] = v;
            }
        }
    }
}

// ---------------- combine ----------------

__global__ void k_combine(const float* __restrict__ y,
                          const int* __restrict__ top_idx, const float* __restrict__ top_w,
                          const int* __restrict__ slot_in, const int* __restrict__ offsets,
                          float* __restrict__ out) {
    const int n = blockIdx.x;
    const int e0 = top_idx[n * 2], e1 = top_idx[n * 2 + 1];
    const int s0 = offsets[e0] + slot_in[n * 2];
    const int s1 = offsets[e1] + slot_in[n * 2 + 1];
    const float w0 = top_w[n * 2], w1 = top_w[n * 2 + 1];
    const int d = threadIdx.x * 4;
    const float4 a = *(const float4*)(y + (size_t)s0 * D_ + d);
    const float4 b = *(const float4*)(y + (size_t)s1 * D_ + d);
    float4 o;
    o.x = w0 * a.x + w1 * b.x;
    o.y = w0 * a.y + w1 * b.y;
    o.z = w0 * a.z + w1 * b.z;
    o.w = w0 * a.w + w1 * b.w;
    *(float4*)(out + (size_t)n * D_ + d) = o;
}

// ---------------- launch ----------------

extern "C" void kernel_launch(void* const* d_in, const int* in_sizes, int n_in,
                              void* d_out, int out_size, void* d_ws, size_t ws_size,
                              hipStream_t stream) {
    const float* x  = (const float*)d_in[0];
    const float* gw = (const float*)d_in[1];
    const float* w1 = (const float*)d_in[2];
    const float* w2 = (const float*)d_in[3];
    float* out = (float*)d_out;

    char* ws = (char*)d_ws;
    size_t o = 0;
    auto alloc = [&](size_t b) { size_t r = o; o += (b + 255) & ~(size_t)255; return r; };
    int*   counts  = (int*)(ws + alloc(E_ * 4));
    int*   offsets = (int*)(ws + alloc((E_ + 1) * 4));
    int*   top_idx = (int*)(ws + alloc(2 * N_ * 4));
    float* top_w   = (float*)(ws + alloc(2 * N_ * 4));
    int*   slot_in = (int*)(ws + alloc(2 * N_ * 4));
    int*   perm    = (int*)(ws + alloc(2 * N_ * 4));
    short* xb      = (short*)(ws + alloc((size_t)N_ * D_ * 2));           // 4 MB
    short* w1b     = (short*)(ws + alloc((size_t)E_ * F_ * D_ * 2));      // 64 MB
    short* w2b     = (short*)(ws + alloc((size_t)E_ * D_ * F_ * 2));      // 64 MB
    short* h       = (short*)(ws + alloc((size_t)2 * N_ * F_ * 2));       // 32 MB
    float* yb      = (float*)(ws + alloc((size_t)2 * N_ * D_ * 4));       // 16 MB

    // bulk fp32 -> bf16 conversion (once per call)
    hipLaunchKernelGGL(k_f32_to_bf16, dim3(2048), dim3(256), 0, stream, w1, w1b, E_ * F_ * D_ / 4);
    hipLaunchKernelGGL(k_f32_to_bf16, dim3(2048), dim3(256), 0, stream, w2, w2b, E_ * D_ * F_ / 4);
    hipLaunchKernelGGL(k_f32_to_bf16, dim3(512),  dim3(256), 0, stream, x,  xb,  N_ * D_ / 4);

    // routing
    hipLaunchKernelGGL(k_zero, dim3(1), dim3(64), 0, stream, counts);
    hipLaunchKernelGGL(k_route, dim3(N_ / 4), dim3(256), 0, stream, x, gw, counts, top_idx, top_w, slot_in);
    hipLaunchKernelGGL(k_scan, dim3(1), dim3(64), 0, stream, counts, offsets);
    hipLaunchKernelGGL(k_scatter, dim3((2 * N_ + 255) / 256), dim3(256), 0, stream,
                       top_idx, slot_in, offsets, perm);

    // GEMM1: h = gelu(X_gather @ w1^T)   [rows x F], K = D
    hipLaunchKernelGGL((k_gemm<D_, F_, true, true, true>), dim3(F_ / 128, E_ * 16), dim3(256), 0, stream,
                       xb, w1b, counts, offsets, perm, (void*)h);
    // GEMM2: y = h @ w2^T                [rows x D], K = F
    hipLaunchKernelGGL((k_gemm<F_, D_, false, false, false>), dim3(D_ / 128, E_ * 16), dim3(256), 0, stream,
                       h, w2b, counts, offsets, perm, (void*)yb);

    hipLaunchKernelGGL(k_combine, dim3(N_), dim3(256), 0, stream,
                       yb, top_idx, top_w, slot_in, offsets, out);
}